// Round 15
// baseline (55.592 us; speedup 1.0000x reference)
//
#include <hip/hip_runtime.h>
#include <hip/hip_fp16.h>
#include <cmath>

#define BB 4
#define HH 64
#define WW 64

// ---- LDS pool (per half-row block): 18557 words = 74.2 KB -> 2 blocks/CU ----
// window col-stride 70 halves (35 words, gcd(35,32)=1 -> conflict-free staging writes)
#define OFFW  10140     // [104][33] f32: ox rows 0..51, oy rows 52..103
#define SBW   13572     // [53][35] f32: scores
#define CMAP  15427     // [25][33] f32: per-pixel 5x5 cell weight map
#define FLBC  16252     // fallback counter
#define FLB   16253     // fallback list, 512 x uint2
#define POOLW 18557
// half-indexed bases
#define WIN_H 0         // [5][36 cols][70 stride] fp16 window (12600 halves)
#define TF_H  12600     // t_f [32 px][80] fp16
#define TC_H  15160
#define TM_H  17720     // end 20280 halves
#define AGG_H 34554     // agg [32][80] fp16 (words 17277..18557)
#define PCB_H 20280     // pc out [32][80] fp16, overlays OFFW (dead after coordpack)
#define H1_H  22840     // h1     [32][80] fp16, overlays OFFW

typedef _Float16 f16x8 __attribute__((ext_vector_type(8)));
typedef float    f32x4 __attribute__((ext_vector_type(4)));

// one 16x16 output tile per wave: D = W(64x64 f32 global) x act(PH [px][80] f16) + bias
__device__ inline f32x4 tile_gemm64(const __half* PH, int actH,
                                    const float* __restrict__ W,
                                    const float* __restrict__ Bv,
                                    int m_t, int n_t, int lane) {
    const int row = m_t * 16 + (lane & 15);
    const int kg  = (lane >> 4) * 8;
    const float* wr = W + row * 64 + kg;
    float4 wa0 = *reinterpret_cast<const float4*>(wr);
    float4 wa1 = *reinterpret_cast<const float4*>(wr + 4);
    float4 wb0 = *reinterpret_cast<const float4*>(wr + 32);
    float4 wb1 = *reinterpret_cast<const float4*>(wr + 36);
    f16x8 a0, a1;
    a0[0]=(_Float16)wa0.x; a0[1]=(_Float16)wa0.y; a0[2]=(_Float16)wa0.z; a0[3]=(_Float16)wa0.w;
    a0[4]=(_Float16)wa1.x; a0[5]=(_Float16)wa1.y; a0[6]=(_Float16)wa1.z; a0[7]=(_Float16)wa1.w;
    a1[0]=(_Float16)wb0.x; a1[1]=(_Float16)wb0.y; a1[2]=(_Float16)wb0.z; a1[3]=(_Float16)wb0.w;
    a1[4]=(_Float16)wb1.x; a1[5]=(_Float16)wb1.y; a1[6]=(_Float16)wb1.z; a1[7]=(_Float16)wb1.w;
    const int px = n_t * 16 + (lane & 15);
    f16x8 b0 = *reinterpret_cast<const f16x8*>(&PH[actH + px * 80 + kg]);
    f16x8 b1 = *reinterpret_cast<const f16x8*>(&PH[actH + px * 80 + 32 + kg]);
    f32x4 d;
    const int r0 = m_t * 16 + ((lane >> 4) << 2);
    #pragma unroll
    for (int r = 0; r < 4; ++r) d[r] = Bv[r0 + r];
    d = __builtin_amdgcn_mfma_f32_16x16x32_f16(a0, b0, d, 0, 0, 0);
    d = __builtin_amdgcn_mfma_f32_16x16x32_f16(a1, b1, d, 0, 0, 0);
    return d;
}

// ---------------- fused main: 1 block (8 waves, 512 thr) per HALF row; 2 blocks/CU ----------------
__global__ __launch_bounds__(512, 4) void crossd_main(
    const float* __restrict__ x,
    const float* __restrict__ p_n,
    const float* __restrict__ dwf_w, const float* __restrict__ dwf_b,
    const float* __restrict__ pwf_w, const float* __restrict__ pwf_b,
    const float* __restrict__ dwc_w, const float* __restrict__ dwc_b,
    const float* __restrict__ pwc_w, const float* __restrict__ pwc_b,
    const float* __restrict__ dwm_w, const float* __restrict__ dwm_b,
    const float* __restrict__ pwm_w, const float* __restrict__ pwm_b,
    const float* __restrict__ pc_w, const float* __restrict__ pc_b,
    const float* __restrict__ w1, const float* __restrict__ b1,
    const float* __restrict__ w2, const float* __restrict__ b2,
    float* __restrict__ out)
{
    __shared__ float P[POOLW];
    uint32_t* PU = reinterpret_cast<uint32_t*>(P);
    __half*   PH = reinterpret_cast<__half*>(P);
    const int tid  = threadIdx.x;
    const int lane = tid & 63;
    const int wv   = __builtin_amdgcn_readfirstlane(tid >> 6);   // 0..7
    const int bid = blockIdx.x;                                  // 512 blocks
    const int xh = bid & 1, y = (bid >> 1) & 63, b = bid >> 7;
    const int x0 = xh << 5;                                      // half-row origin
    const int ry0 = min(max(y - 1, 0), 59);                      // window rows ry0..ry0+4
    const float* xb = x + (size_t)b * (64 * HH * WW);            // NCHW batch base

    // ---- phase 0: stage 5-row x 36-col fp16 window DIRECTLY from NCHW x ----
    {
        // idx = (j, c, col), col fastest -> coalesced 144 B row segments per (j,c)
        for (int idx = tid; idx < 5 * 64 * 36; idx += 512) {
            int j   = idx / (64 * 36);
            int rem = idx - j * (64 * 36);
            int c   = rem / 36;
            int col = rem - c * 36;
            int gcol = min(max(x0 - 1 + col, 0), 63);
            float v = xb[((size_t)c * HH + (ry0 + j)) * WW + gcol];
            PH[(j * 36 + col) * 70 + c] = __float2half(v);
        }
        for (int i = tid; i < 25 * 33 + 1; i += 512) P[CMAP + i] = 0.0f;  // CMAP + FLBC
    }
    __syncthreads();   // B0

    // ---- depthwise 3x3 from window: wave = 4 px, lane = ch; fp16 t-buffers [32][80] ----
    {
        const int c = lane;
        float wf9[9], wc9[9], wm9[9];
        #pragma unroll
        for (int k9 = 0; k9 < 9; ++k9) {
            wf9[k9] = dwf_w[c * 9 + k9];
            wc9[k9] = dwc_w[c * 9 + k9];
            wm9[k9] = dwm_w[c * 9 + k9];
        }
        const float bf = dwf_b[c], bc = dwc_b[c], bm = dwm_b[c];
        #pragma unroll
        for (int i = 0; i < 4; ++i) {
            const int pl = wv * 4 + i;          // local px
            const int pg = x0 + pl;             // global px
            float af = bf, ac = bc, am = bm;
            #pragma unroll
            for (int dy = 0; dy < 3; ++dy) {
                int yy = y + dy - 1;
                if (yy < 0 || yy >= HH) continue;
                int j = yy - ry0;
                #pragma unroll
                for (int dx = 0; dx < 3; ++dx) {
                    int xx = pg + dx - 1;
                    if (xx < 0 || xx >= WW) continue;
                    int co = xx - x0 + 1;       // window col 0..33
                    float v = __half2float(PH[(j * 36 + co) * 70 + c]);
                    int k = dy * 3 + dx;
                    af = fmaf(v, wf9[k], af);
                    ac = fmaf(v, wc9[k], ac);
                    am = fmaf(v, wm9[k], am);
                }
            }
            PH[TF_H + pl * 80 + c] = __float2half(af);
            PH[TC_H + pl * 80 + c] = __float2half(ac);
            PH[TM_H + pl * 80 + c] = __float2half(am);
        }
    }
    __syncthreads();   // B1

    // ---- fused f+c+m pointwise via MFMA: 11 m-tiles x 2 n-tiles over 8 waves ----
    {
        const int n_t = wv & 1;
        const int g   = wv >> 1;
        #pragma unroll
        for (int t = 0; t < 3; ++t) {
            const int m_t = g + t * 4;
            if (m_t < 11) {
                const float *Wb, *Bvb; int rows, actH, r0b, br;
                if (m_t < 2)      { Wb=pwf_w; Bvb=pwf_b; rows=32; actH=TF_H; r0b=m_t*16;     br=0; }
                else if (m_t < 7) { Wb=pwc_w; Bvb=pwc_b; rows=72; actH=TC_H; r0b=(m_t-2)*16; br=1; }
                else              { Wb=pwm_w; Bvb=pwm_b; rows=53; actH=TM_H; r0b=(m_t-7)*16; br=2; }
                const int rl  = min(r0b + (lane & 15), rows - 1);
                const int kg  = (lane >> 4) * 8;
                const float* wr = Wb + rl * 64 + kg;
                float4 wa0 = *reinterpret_cast<const float4*>(wr);
                float4 wa1 = *reinterpret_cast<const float4*>(wr + 4);
                float4 wb0 = *reinterpret_cast<const float4*>(wr + 32);
                float4 wb1 = *reinterpret_cast<const float4*>(wr + 36);
                f16x8 a0, a1;
                a0[0]=(_Float16)wa0.x; a0[1]=(_Float16)wa0.y; a0[2]=(_Float16)wa0.z; a0[3]=(_Float16)wa0.w;
                a0[4]=(_Float16)wa1.x; a0[5]=(_Float16)wa1.y; a0[6]=(_Float16)wa1.z; a0[7]=(_Float16)wa1.w;
                a1[0]=(_Float16)wb0.x; a1[1]=(_Float16)wb0.y; a1[2]=(_Float16)wb0.z; a1[3]=(_Float16)wb0.w;
                a1[4]=(_Float16)wb1.x; a1[5]=(_Float16)wb1.y; a1[6]=(_Float16)wb1.z; a1[7]=(_Float16)wb1.w;
                const int px = n_t * 16 + (lane & 15);
                f16x8 b0 = *reinterpret_cast<const f16x8*>(&PH[actH + px * 80 + kg]);
                f16x8 b1 = *reinterpret_cast<const f16x8*>(&PH[actH + px * 80 + 32 + kg]);
                f32x4 d;
                const int rr0 = r0b + ((lane >> 4) << 2);
                #pragma unroll
                for (int r = 0; r < 4; ++r) d[r] = Bvb[min(rr0 + r, rows - 1)];
                d = __builtin_amdgcn_mfma_f32_16x16x32_f16(a0, b0, d, 0, 0, 0);
                d = __builtin_amdgcn_mfma_f32_16x16x32_f16(a1, b1, d, 0, 0, 0);
                #pragma unroll
                for (int r = 0; r < 4; ++r) {
                    const int rb = rr0 + r;
                    if (rb < rows) {
                        const float v = d[r];
                        if (br == 2)      P[SBW + rb * 35 + px] = v;
                        else {
                            int og = (br == 0) ? rb : 32 + rb;
                            P[OFFW + og * 33 + px] = v;
                        }
                    }
                }
            }
        }
    }
    __syncthreads();   // B2

    // ---- fused gated-softmax + coordpack (cell-map accumulate): wave owns 4 px ----
    #pragma unroll 1
    for (int i = 0; i < 4; ++i) {
        const int pl = wv * 4 + i;
        const float sp = P[SBW + 52 * 35 + pl];
        float z = -1e30f;
        if (lane < 52) {
            float s  = P[SBW + lane * 35 + pl];
            float sg = 1.0f / (1.0f + __expf(-(s - sp) * 10.0f));
            z = s + __logf(sg + 1e-10f);
        }
        float mx = z;
        #pragma unroll
        for (int d = 32; d >= 1; d >>= 1) mx = fmaxf(mx, __shfl_xor(mx, d));
        float e = (lane < 52) ? __expf(z - mx) : 0.0f;
        float sm = e;
        #pragma unroll
        for (int d = 32; d >= 1; d >>= 1) sm += __shfl_xor(sm, d);
        if (lane < 52) {
            const float mo = e / sm;
            const int pg = x0 + pl;
            float sx = (float)pg + p_n[lane]      + P[OFFW + lane * 33 + pl];
            float sy = (float)y  + p_n[52 + lane] + P[OFFW + (52 + lane) * 33 + pl];
            float x0f = floorf(sx), y0f = floorf(sy);
            float wx1 = sx - x0f, wy1 = sy - y0f;
            float wx0 = 1.0f - wx1, wy0 = 1.0f - wy1;
            int xi = (int)x0f, yi = (int)y0f;
            bool vx0 = (xi >= 0)  & (xi <= 63);
            bool vx1 = (xi >= -1) & (xi <= 62);
            bool vy0 = (yi >= 0)  & (yi <= 63);
            bool vy1 = (yi >= -1) & (yi <= 62);
            float m00 = (vy0 & vx0) ? mo * wy0 * wx0 : 0.0f;
            float m01 = (vy0 & vx1) ? mo * wy0 * wx1 : 0.0f;
            float m10 = (vy1 & vx0) ? mo * wy1 * wx0 : 0.0f;
            float m11 = (vy1 & vx1) ? mo * wy1 * wx1 : 0.0f;
            const int i0 = xi - pg + 1, j0 = yi - ry0;
            #define PUSH(m, jj, ii, gx, gy) \
                if (m != 0.0f) { \
                    if ((jj) >= 0 && (jj) <= 4 && (ii) >= 0 && (ii) <= 4) { \
                        atomicAdd(&P[CMAP + ((jj) * 5 + (ii)) * 33 + pl], m); \
                    } else { \
                        uint32_t a = (uint32_t)((gy) * 64 + (gx)); \
                        uint32_t sl = atomicAdd(&PU[FLBC], 1u); \
                        if (sl < 512u) { \
                            PU[FLB + sl * 2]     = a | ((uint32_t)pl << 16); \
                            PU[FLB + sl * 2 + 1] = __float_as_uint(m); \
                        } \
                    } \
                }
            PUSH(m00, j0,     i0,     xi,     yi);
            PUSH(m01, j0,     i0 + 1, xi + 1, yi);
            PUSH(m10, j0 + 1, i0,     xi,     yi + 1);
            PUSH(m11, j0 + 1, i0 + 1, xi + 1, yi + 1);
            #undef PUSH
        }
    }
    __syncthreads();   // B3

    // ---- 25-cell gather: W[cell][px] broadcast x window b64; agg -> fp16 [32][80] ----
    {
        const int sub = lane >> 4;
        const int c4  = lane & 15;
        const int spx = wv * 4 + sub;        // local px
        const int spg = x0 + spx;            // global px
        int co[5];
        #pragma unroll
        for (int i = 0; i < 5; ++i) co[i] = min(max(spg - 1 + i, 0), 63) - x0 + 1;
        float4 agg = make_float4(0.f, 0.f, 0.f, 0.f);
        #pragma unroll
        for (int j = 0; j < 5; ++j) {
            #pragma unroll
            for (int i = 0; i < 5; ++i) {
                float w = P[CMAP + (j * 5 + i) * 33 + spx];
                uint2 u = *reinterpret_cast<const uint2*>(&PH[(j * 36 + co[i]) * 70 + c4 * 4]);
                __half2 hlo = *reinterpret_cast<const __half2*>(&u.x);
                __half2 hhi = *reinterpret_cast<const __half2*>(&u.y);
                float2 flo = __half22float2(hlo), fhi = __half22float2(hhi);
                agg.x = fmaf(w, flo.x, agg.x); agg.y = fmaf(w, flo.y, agg.y);
                agg.z = fmaf(w, fhi.x, agg.z); agg.w = fmaf(w, fhi.y, agg.w);
            }
        }
        // rare out-of-neighborhood fallback (normally count == 0); NCHW scalar reads
        const int cnt = min((int)PU[FLBC], 512);
        for (int e = 0; e < cnt; ++e) {
            uint32_t ea = PU[FLB + e * 2];
            float m = __uint_as_float(PU[FLB + e * 2 + 1]);
            if ((int)(ea >> 16) == spx) {
                int gy = (int)((ea & 0xFFFFu) >> 6), gx = (int)(ea & 63u);
                float v0 = xb[((size_t)(c4 * 4 + 0) * HH + gy) * WW + gx];
                float v1 = xb[((size_t)(c4 * 4 + 1) * HH + gy) * WW + gx];
                float v2 = xb[((size_t)(c4 * 4 + 2) * HH + gy) * WW + gx];
                float v3 = xb[((size_t)(c4 * 4 + 3) * HH + gy) * WW + gx];
                agg.x = fmaf(m, v0, agg.x); agg.y = fmaf(m, v1, agg.y);
                agg.z = fmaf(m, v2, agg.z); agg.w = fmaf(m, v3, agg.w);
            }
        }
        __half2 p0 = __floats2half2_rn(agg.x, agg.y);
        __half2 p1 = __floats2half2_rn(agg.z, agg.w);
        uint2 pk2;
        pk2.x = *reinterpret_cast<uint32_t*>(&p0);
        pk2.y = *reinterpret_cast<uint32_t*>(&p1);
        *reinterpret_cast<uint2*>(&PH[AGG_H + spx * 80 + c4 * 4]) = pk2;
    }
    __syncthreads();   // B4

    // ---- pc 1x1 via MFMA: AGG -> PCB ----
    {
        f32x4 d = tile_gemm64(PH, AGG_H, pc_w, pc_b, wv >> 1, wv & 1, lane);
        const int px = (wv & 1) * 16 + (lane & 15);
        const int o0 = (wv >> 1) * 16 + ((lane >> 4) << 2);
        __half2 p0 = __floats2half2_rn(d[0], d[1]);
        __half2 p1 = __floats2half2_rn(d[2], d[3]);
        uint2 pk2;
        pk2.x = *reinterpret_cast<uint32_t*>(&p0);
        pk2.y = *reinterpret_cast<uint32_t*>(&p1);
        *reinterpret_cast<uint2*>(&PH[PCB_H + px * 80 + o0]) = pk2;
    }
    __syncthreads();   // B5

    // ---- mlp1 (relu) via MFMA: PCB -> H1 ----
    {
        f32x4 d = tile_gemm64(PH, PCB_H, w1, b1, wv >> 1, wv & 1, lane);
        #pragma unroll
        for (int r = 0; r < 4; ++r) d[r] = fmaxf(d[r], 0.0f);
        const int px = (wv & 1) * 16 + (lane & 15);
        const int o0 = (wv >> 1) * 16 + ((lane >> 4) << 2);
        __half2 p0 = __floats2half2_rn(d[0], d[1]);
        __half2 p1 = __floats2half2_rn(d[2], d[3]);
        uint2 pk2;
        pk2.x = *reinterpret_cast<uint32_t*>(&p0);
        pk2.y = *reinterpret_cast<uint32_t*>(&p1);
        *reinterpret_cast<uint2*>(&PH[H1_H + px * 80 + o0]) = pk2;
    }
    __syncthreads();   // B6

    // ---- mlp2 via MFMA + residual + NCHW store ----
    {
        f32x4 d = tile_gemm64(PH, H1_H, w2, b2, wv >> 1, wv & 1, lane);
        const int px = (wv & 1) * 16 + (lane & 15);
        const int o0 = (wv >> 1) * 16 + ((lane >> 4) << 2);
        #pragma unroll
        for (int r = 0; r < 4; ++r) {
            const int o = o0 + r;
            size_t idx = (((size_t)b * 64 + o) * 64 + y) * 64 + x0 + px;
            out[idx] = d[r] + x[idx];
        }
    }
}

extern "C" void kernel_launch(void* const* d_in, const int* in_sizes, int n_in,
                              void* d_out, int out_size, void* d_ws, size_t ws_size,
                              hipStream_t stream) {
    const float* x     = (const float*)d_in[0];
    const float* p_n   = (const float*)d_in[1];
    const float* dwf_w = (const float*)d_in[2];
    const float* dwf_b = (const float*)d_in[3];
    const float* pwf_w = (const float*)d_in[4];
    const float* pwf_b = (const float*)d_in[5];
    const float* dwc_w = (const float*)d_in[6];
    const float* dwc_b = (const float*)d_in[7];
    const float* pwc_w = (const float*)d_in[8];
    const float* pwc_b = (const float*)d_in[9];
    const float* dwm_w = (const float*)d_in[10];
    const float* dwm_b = (const float*)d_in[11];
    const float* pwm_w = (const float*)d_in[12];
    const float* pwm_b = (const float*)d_in[13];
    const float* pc_w  = (const float*)d_in[14];
    const float* pc_b  = (const float*)d_in[15];
    const float* w1    = (const float*)d_in[16];
    const float* b1    = (const float*)d_in[17];
    const float* w2    = (const float*)d_in[18];
    const float* b2    = (const float*)d_in[19];

    float* outp = (float*)d_out;

    hipLaunchKernelGGL(crossd_main, dim3(BB * HH * 2), dim3(512), 0, stream,
                       x, p_n,
                       dwf_w, dwf_b, pwf_w, pwf_b,
                       dwc_w, dwc_b, pwc_w, pwc_b,
                       dwm_w, dwm_b, pwm_w, pwm_b,
                       pc_w, pc_b, w1, b1, w2, b2, outp);
}

// Round 16
// 46.086 us; speedup vs baseline: 1.2063x; 1.2063x over previous
//
#include <hip/hip_runtime.h>
#include <hip/hip_fp16.h>
#include <cmath>

#define BB 4
#define HH 64
#define WW 64

// ---- LDS pool (per half-row block): 18377 words = 73.5 KB -> 2 blocks/CU ----
#define OFFW  9960      // [104][33] f32: ox rows 0..51, oy rows 52..103
#define SBW   13392     // [53][35] f32: scores
#define CMAP  15247     // [25][33] f32: per-pixel 5x5 cell weight map
#define FLBC  16072     // fallback counter
#define FLB   16073     // fallback list, 512 x uint2
#define POOLW 18377
// half-indexed bases
#define WIN_H 0         // [5][36 cols][68 stride] fp16 window (12240 halves)
#define TF_H  12240     // t_f [32 px][80] fp16
#define TC_H  14800
#define TM_H  17360     // end 19920 halves
#define AGG_H 34194     // agg [32][80] fp16 (words 17097..18377)
#define PCB_H 19920     // pc out [32][80] fp16, overlays OFFW (dead after coordpack)
#define H1_H  22480     // h1     [32][80] fp16, overlays OFFW

typedef _Float16 f16x8 __attribute__((ext_vector_type(8)));
typedef float    f32x4 __attribute__((ext_vector_type(4)));

// one 16x16 output tile per wave: D = W(64x64 f32 global) x act(PH [px][80] f16) + bias
__device__ inline f32x4 tile_gemm64(const __half* PH, int actH,
                                    const float* __restrict__ W,
                                    const float* __restrict__ Bv,
                                    int m_t, int n_t, int lane) {
    const int row = m_t * 16 + (lane & 15);
    const int kg  = (lane >> 4) * 8;
    const float* wr = W + row * 64 + kg;
    float4 wa0 = *reinterpret_cast<const float4*>(wr);
    float4 wa1 = *reinterpret_cast<const float4*>(wr + 4);
    float4 wb0 = *reinterpret_cast<const float4*>(wr + 32);
    float4 wb1 = *reinterpret_cast<const float4*>(wr + 36);
    f16x8 a0, a1;
    a0[0]=(_Float16)wa0.x; a0[1]=(_Float16)wa0.y; a0[2]=(_Float16)wa0.z; a0[3]=(_Float16)wa0.w;
    a0[4]=(_Float16)wa1.x; a0[5]=(_Float16)wa1.y; a0[6]=(_Float16)wa1.z; a0[7]=(_Float16)wa1.w;
    a1[0]=(_Float16)wb0.x; a1[1]=(_Float16)wb0.y; a1[2]=(_Float16)wb0.z; a1[3]=(_Float16)wb0.w;
    a1[4]=(_Float16)wb1.x; a1[5]=(_Float16)wb1.y; a1[6]=(_Float16)wb1.z; a1[7]=(_Float16)wb1.w;
    const int px = n_t * 16 + (lane & 15);
    f16x8 b0 = *reinterpret_cast<const f16x8*>(&PH[actH + px * 80 + kg]);
    f16x8 b1 = *reinterpret_cast<const f16x8*>(&PH[actH + px * 80 + 32 + kg]);
    f32x4 d;
    const int r0 = m_t * 16 + ((lane >> 4) << 2);
    #pragma unroll
    for (int r = 0; r < 4; ++r) d[r] = Bv[r0 + r];
    d = __builtin_amdgcn_mfma_f32_16x16x32_f16(a0, b0, d, 0, 0, 0);
    d = __builtin_amdgcn_mfma_f32_16x16x32_f16(a1, b1, d, 0, 0, 0);
    return d;
}

// ---------------- fused main: 1 block (8 waves, 512 thr) per HALF row; 2 blocks/CU ----------------
__global__ __launch_bounds__(512, 4) void crossd_main(
    const float* __restrict__ x,
    const float* __restrict__ p_n,
    const float* __restrict__ dwf_w, const float* __restrict__ dwf_b,
    const float* __restrict__ pwf_w, const float* __restrict__ pwf_b,
    const float* __restrict__ dwc_w, const float* __restrict__ dwc_b,
    const float* __restrict__ pwc_w, const float* __restrict__ pwc_b,
    const float* __restrict__ dwm_w, const float* __restrict__ dwm_b,
    const float* __restrict__ pwm_w, const float* __restrict__ pwm_b,
    const float* __restrict__ pc_w, const float* __restrict__ pc_b,
    const float* __restrict__ w1, const float* __restrict__ b1,
    const float* __restrict__ w2, const float* __restrict__ b2,
    float* __restrict__ out)
{
    __shared__ float P[POOLW];
    uint32_t* PU = reinterpret_cast<uint32_t*>(P);
    __half*   PH = reinterpret_cast<__half*>(P);
    const int tid  = threadIdx.x;
    const int lane = tid & 63;
    const int wv   = __builtin_amdgcn_readfirstlane(tid >> 6);   // 0..7
    const int bid = blockIdx.x;                                  // 512 blocks
    const int xh = bid & 1, y = (bid >> 1) & 63, b = bid >> 7;
    const int x0 = xh << 5;                                      // half-row origin
    const int ry0 = min(max(y - 1, 0), 59);                      // window rows ry0..ry0+4
    const float* xb = x + (size_t)b * (64 * HH * WW);            // NCHW batch base

    // ---- phase 0: stage 5-row x 36-col fp16 window DIRECTLY from NCHW x ----
    {
        // idx = (j, c, col), col fastest -> coalesced 144 B row segments per (j,c)
        for (int idx = tid; idx < 5 * 64 * 36; idx += 512) {
            int j   = idx / (64 * 36);
            int rem = idx - j * (64 * 36);
            int c   = rem / 36;
            int col = rem - c * 36;
            int gcol = min(max(x0 - 1 + col, 0), 63);
            float v = xb[((size_t)c * HH + (ry0 + j)) * WW + gcol];
            PH[(j * 36 + col) * 68 + c] = __float2half(v);
        }
        for (int i = tid; i < 25 * 33 + 1; i += 512) P[CMAP + i] = 0.0f;  // CMAP + FLBC
    }
    __syncthreads();   // B0

    // ---- depthwise 3x3 from window: wave = 4 px, lane = ch; fp16 t-buffers [32][80] ----
    {
        const int c = lane;
        float wf9[9], wc9[9], wm9[9];
        #pragma unroll
        for (int k9 = 0; k9 < 9; ++k9) {
            wf9[k9] = dwf_w[c * 9 + k9];
            wc9[k9] = dwc_w[c * 9 + k9];
            wm9[k9] = dwm_w[c * 9 + k9];
        }
        const float bf = dwf_b[c], bc = dwc_b[c], bm = dwm_b[c];
        #pragma unroll
        for (int i = 0; i < 4; ++i) {
            const int pl = wv * 4 + i;          // local px
            const int pg = x0 + pl;             // global px
            float af = bf, ac = bc, am = bm;
            #pragma unroll
            for (int dy = 0; dy < 3; ++dy) {
                int yy = y + dy - 1;
                if (yy < 0 || yy >= HH) continue;
                int j = yy - ry0;
                #pragma unroll
                for (int dx = 0; dx < 3; ++dx) {
                    int xx = pg + dx - 1;
                    if (xx < 0 || xx >= WW) continue;
                    int co = xx - x0 + 1;       // window col 0..33
                    float v = __half2float(PH[(j * 36 + co) * 68 + c]);
                    int k = dy * 3 + dx;
                    af = fmaf(v, wf9[k], af);
                    ac = fmaf(v, wc9[k], ac);
                    am = fmaf(v, wm9[k], am);
                }
            }
            PH[TF_H + pl * 80 + c] = __float2half(af);
            PH[TC_H + pl * 80 + c] = __float2half(ac);
            PH[TM_H + pl * 80 + c] = __float2half(am);
        }
    }
    __syncthreads();   // B1

    // ---- fused f+c+m pointwise via MFMA: 11 m-tiles x 2 n-tiles over 8 waves ----
    {
        const int n_t = wv & 1;
        const int g   = wv >> 1;
        #pragma unroll
        for (int t = 0; t < 3; ++t) {
            const int m_t = g + t * 4;
            if (m_t < 11) {
                const float *Wb, *Bvb; int rows, actH, r0b, br;
                if (m_t < 2)      { Wb=pwf_w; Bvb=pwf_b; rows=32; actH=TF_H; r0b=m_t*16;     br=0; }
                else if (m_t < 7) { Wb=pwc_w; Bvb=pwc_b; rows=72; actH=TC_H; r0b=(m_t-2)*16; br=1; }
                else              { Wb=pwm_w; Bvb=pwm_b; rows=53; actH=TM_H; r0b=(m_t-7)*16; br=2; }
                const int rl  = min(r0b + (lane & 15), rows - 1);
                const int kg  = (lane >> 4) * 8;
                const float* wr = Wb + rl * 64 + kg;
                float4 wa0 = *reinterpret_cast<const float4*>(wr);
                float4 wa1 = *reinterpret_cast<const float4*>(wr + 4);
                float4 wb0 = *reinterpret_cast<const float4*>(wr + 32);
                float4 wb1 = *reinterpret_cast<const float4*>(wr + 36);
                f16x8 a0, a1;
                a0[0]=(_Float16)wa0.x; a0[1]=(_Float16)wa0.y; a0[2]=(_Float16)wa0.z; a0[3]=(_Float16)wa0.w;
                a0[4]=(_Float16)wa1.x; a0[5]=(_Float16)wa1.y; a0[6]=(_Float16)wa1.z; a0[7]=(_Float16)wa1.w;
                a1[0]=(_Float16)wb0.x; a1[1]=(_Float16)wb0.y; a1[2]=(_Float16)wb0.z; a1[3]=(_Float16)wb0.w;
                a1[4]=(_Float16)wb1.x; a1[5]=(_Float16)wb1.y; a1[6]=(_Float16)wb1.z; a1[7]=(_Float16)wb1.w;
                const int px = n_t * 16 + (lane & 15);
                f16x8 b0 = *reinterpret_cast<const f16x8*>(&PH[actH + px * 80 + kg]);
                f16x8 b1 = *reinterpret_cast<const f16x8*>(&PH[actH + px * 80 + 32 + kg]);
                f32x4 d;
                const int rr0 = r0b + ((lane >> 4) << 2);
                #pragma unroll
                for (int r = 0; r < 4; ++r) d[r] = Bvb[min(rr0 + r, rows - 1)];
                d = __builtin_amdgcn_mfma_f32_16x16x32_f16(a0, b0, d, 0, 0, 0);
                d = __builtin_amdgcn_mfma_f32_16x16x32_f16(a1, b1, d, 0, 0, 0);
                #pragma unroll
                for (int r = 0; r < 4; ++r) {
                    const int rb = rr0 + r;
                    if (rb < rows) {
                        const float v = d[r];
                        if (br == 2)      P[SBW + rb * 35 + px] = v;
                        else {
                            int og = (br == 0) ? rb : 32 + rb;
                            P[OFFW + og * 33 + px] = v;
                        }
                    }
                }
            }
        }
    }
    __syncthreads();   // B2

    // ---- fused gated-softmax + coordpack (cell-map accumulate): wave owns 4 px ----
    #pragma unroll 1
    for (int i = 0; i < 4; ++i) {
        const int pl = wv * 4 + i;
        const float sp = P[SBW + 52 * 35 + pl];
        float z = -1e30f;
        if (lane < 52) {
            float s  = P[SBW + lane * 35 + pl];
            float sg = 1.0f / (1.0f + __expf(-(s - sp) * 10.0f));
            z = s + __logf(sg + 1e-10f);
        }
        float mx = z;
        #pragma unroll
        for (int d = 32; d >= 1; d >>= 1) mx = fmaxf(mx, __shfl_xor(mx, d));
        float e = (lane < 52) ? __expf(z - mx) : 0.0f;
        float sm = e;
        #pragma unroll
        for (int d = 32; d >= 1; d >>= 1) sm += __shfl_xor(sm, d);
        if (lane < 52) {
            const float mo = e / sm;
            const int pg = x0 + pl;
            float sx = (float)pg + p_n[lane]      + P[OFFW + lane * 33 + pl];
            float sy = (float)y  + p_n[52 + lane] + P[OFFW + (52 + lane) * 33 + pl];
            float x0f = floorf(sx), y0f = floorf(sy);
            float wx1 = sx - x0f, wy1 = sy - y0f;
            float wx0 = 1.0f - wx1, wy0 = 1.0f - wy1;
            int xi = (int)x0f, yi = (int)y0f;
            bool vx0 = (xi >= 0)  & (xi <= 63);
            bool vx1 = (xi >= -1) & (xi <= 62);
            bool vy0 = (yi >= 0)  & (yi <= 63);
            bool vy1 = (yi >= -1) & (yi <= 62);
            float m00 = (vy0 & vx0) ? mo * wy0 * wx0 : 0.0f;
            float m01 = (vy0 & vx1) ? mo * wy0 * wx1 : 0.0f;
            float m10 = (vy1 & vx0) ? mo * wy1 * wx0 : 0.0f;
            float m11 = (vy1 & vx1) ? mo * wy1 * wx1 : 0.0f;
            const int i0 = xi - pg + 1, j0 = yi - ry0;
            #define PUSH(m, jj, ii, gx, gy) \
                if (m != 0.0f) { \
                    if ((jj) >= 0 && (jj) <= 4 && (ii) >= 0 && (ii) <= 4) { \
                        atomicAdd(&P[CMAP + ((jj) * 5 + (ii)) * 33 + pl], m); \
                    } else { \
                        uint32_t a = (uint32_t)((gy) * 64 + (gx)); \
                        uint32_t sl = atomicAdd(&PU[FLBC], 1u); \
                        if (sl < 512u) { \
                            PU[FLB + sl * 2]     = a | ((uint32_t)pl << 16); \
                            PU[FLB + sl * 2 + 1] = __float_as_uint(m); \
                        } \
                    } \
                }
            PUSH(m00, j0,     i0,     xi,     yi);
            PUSH(m01, j0,     i0 + 1, xi + 1, yi);
            PUSH(m10, j0 + 1, i0,     xi,     yi + 1);
            PUSH(m11, j0 + 1, i0 + 1, xi + 1, yi + 1);
            #undef PUSH
        }
    }
    __syncthreads();   // B3

    // ---- 25-cell gather: W[cell][px] broadcast x window b64; agg -> fp16 [32][80] ----
    {
        const int sub = lane >> 4;
        const int c4  = lane & 15;
        const int spx = wv * 4 + sub;        // local px
        const int spg = x0 + spx;            // global px
        int co[5];
        #pragma unroll
        for (int i = 0; i < 5; ++i) co[i] = min(max(spg - 1 + i, 0), 63) - x0 + 1;
        float4 agg = make_float4(0.f, 0.f, 0.f, 0.f);
        #pragma unroll
        for (int j = 0; j < 5; ++j) {
            #pragma unroll
            for (int i = 0; i < 5; ++i) {
                float w = P[CMAP + (j * 5 + i) * 33 + spx];
                uint2 u = *reinterpret_cast<const uint2*>(&PH[(j * 36 + co[i]) * 68 + c4 * 4]);
                __half2 hlo = *reinterpret_cast<const __half2*>(&u.x);
                __half2 hhi = *reinterpret_cast<const __half2*>(&u.y);
                float2 flo = __half22float2(hlo), fhi = __half22float2(hhi);
                agg.x = fmaf(w, flo.x, agg.x); agg.y = fmaf(w, flo.y, agg.y);
                agg.z = fmaf(w, fhi.x, agg.z); agg.w = fmaf(w, fhi.y, agg.w);
            }
        }
        // rare out-of-neighborhood fallback (normally count == 0); NCHW scalar reads
        const int cnt = min((int)PU[FLBC], 512);
        for (int e = 0; e < cnt; ++e) {
            uint32_t ea = PU[FLB + e * 2];
            float m = __uint_as_float(PU[FLB + e * 2 + 1]);
            if ((int)(ea >> 16) == spx) {
                int gy = (int)((ea & 0xFFFFu) >> 6), gx = (int)(ea & 63u);
                float v0 = xb[((size_t)(c4 * 4 + 0) * HH + gy) * WW + gx];
                float v1 = xb[((size_t)(c4 * 4 + 1) * HH + gy) * WW + gx];
                float v2 = xb[((size_t)(c4 * 4 + 2) * HH + gy) * WW + gx];
                float v3 = xb[((size_t)(c4 * 4 + 3) * HH + gy) * WW + gx];
                agg.x = fmaf(m, v0, agg.x); agg.y = fmaf(m, v1, agg.y);
                agg.z = fmaf(m, v2, agg.z); agg.w = fmaf(m, v3, agg.w);
            }
        }
        __half2 p0 = __floats2half2_rn(agg.x, agg.y);
        __half2 p1 = __floats2half2_rn(agg.z, agg.w);
        uint2 pk2;
        pk2.x = *reinterpret_cast<uint32_t*>(&p0);
        pk2.y = *reinterpret_cast<uint32_t*>(&p1);
        *reinterpret_cast<uint2*>(&PH[AGG_H + spx * 80 + c4 * 4]) = pk2;
    }
    __syncthreads();   // B4

    // ---- pc 1x1 via MFMA: AGG -> PCB ----
    {
        f32x4 d = tile_gemm64(PH, AGG_H, pc_w, pc_b, wv >> 1, wv & 1, lane);
        const int px = (wv & 1) * 16 + (lane & 15);
        const int o0 = (wv >> 1) * 16 + ((lane >> 4) << 2);
        __half2 p0 = __floats2half2_rn(d[0], d[1]);
        __half2 p1 = __floats2half2_rn(d[2], d[3]);
        uint2 pk2;
        pk2.x = *reinterpret_cast<uint32_t*>(&p0);
        pk2.y = *reinterpret_cast<uint32_t*>(&p1);
        *reinterpret_cast<uint2*>(&PH[PCB_H + px * 80 + o0]) = pk2;
    }
    __syncthreads();   // B5

    // ---- mlp1 (relu) via MFMA: PCB -> H1 ----
    {
        f32x4 d = tile_gemm64(PH, PCB_H, w1, b1, wv >> 1, wv & 1, lane);
        #pragma unroll
        for (int r = 0; r < 4; ++r) d[r] = fmaxf(d[r], 0.0f);
        const int px = (wv & 1) * 16 + (lane & 15);
        const int o0 = (wv >> 1) * 16 + ((lane >> 4) << 2);
        __half2 p0 = __floats2half2_rn(d[0], d[1]);
        __half2 p1 = __floats2half2_rn(d[2], d[3]);
        uint2 pk2;
        pk2.x = *reinterpret_cast<uint32_t*>(&p0);
        pk2.y = *reinterpret_cast<uint32_t*>(&p1);
        *reinterpret_cast<uint2*>(&PH[H1_H + px * 80 + o0]) = pk2;
    }
    __syncthreads();   // B6

    // ---- mlp2 via MFMA + residual + NCHW store ----
    {
        f32x4 d = tile_gemm64(PH, H1_H, w2, b2, wv >> 1, wv & 1, lane);
        const int px = (wv & 1) * 16 + (lane & 15);
        const int o0 = (wv >> 1) * 16 + ((lane >> 4) << 2);
        #pragma unroll
        for (int r = 0; r < 4; ++r) {
            const int o = o0 + r;
            size_t idx = (((size_t)b * 64 + o) * 64 + y) * 64 + x0 + px;
            out[idx] = d[r] + x[idx];
        }
    }
}

extern "C" void kernel_launch(void* const* d_in, const int* in_sizes, int n_in,
                              void* d_out, int out_size, void* d_ws, size_t ws_size,
                              hipStream_t stream) {
    const float* x     = (const float*)d_in[0];
    const float* p_n   = (const float*)d_in[1];
    const float* dwf_w = (const float*)d_in[2];
    const float* dwf_b = (const float*)d_in[3];
    const float* pwf_w = (const float*)d_in[4];
    const float* pwf_b = (const float*)d_in[5];
    const float* dwc_w = (const float*)d_in[6];
    const float* dwc_b = (const float*)d_in[7];
    const float* pwc_w = (const float*)d_in[8];
    const float* pwc_b = (const float*)d_in[9];
    const float* dwm_w = (const float*)d_in[10];
    const float* dwm_b = (const float*)d_in[11];
    const float* pwm_w = (const float*)d_in[12];
    const float* pwm_b = (const float*)d_in[13];
    const float* pc_w  = (const float*)d_in[14];
    const float* pc_b  = (const float*)d_in[15];
    const float* w1    = (const float*)d_in[16];
    const float* b1    = (const float*)d_in[17];
    const float* w2    = (const float*)d_in[18];
    const float* b2    = (const float*)d_in[19];

    float* outp = (float*)d_out;

    hipLaunchKernelGGL(crossd_main, dim3(BB * HH * 2), dim3(512), 0, stream,
                       x, p_n,
                       dwf_w, dwf_b, pwf_w, pwf_b,
                       dwc_w, dwc_b, pwc_w, pwc_b,
                       dwm_w, dwm_b, pwm_w, pwm_b,
                       pc_w, pc_b, w1, b1, w2, b2, outp);
}

// Round 17
// 45.336 us; speedup vs baseline: 1.2262x; 1.0166x over previous
//
#include <hip/hip_runtime.h>
#include <hip/hip_fp16.h>
#include <cmath>

#define BB 4
#define HH 64
#define WW 64

// ---- LDS pool (per half-row block): 18377 words = 73.5 KB -> 2 blocks/CU ----
#define OFFW  9960      // [104][33] f32: ox rows 0..51, oy rows 52..103
#define SBW   13392     // [53][35] f32: scores
#define CMAP  15247     // [25][33] f32: per-pixel 5x5 cell weight map
#define FLBC  16072     // fallback counter
#define FLB   16073     // fallback list, 512 x uint2
#define POOLW 18377
// half-indexed bases
#define WIN_H 0         // [5][36 cols][68 stride] fp16 window (12240 halves)
#define TF_H  12240     // t_f [32 px][80] fp16
#define TC_H  14800
#define TM_H  17360     // end 19920 halves
#define AGG_H 34194     // agg [32][80] fp16 (words 17097..18377)
#define PCB_H 19920     // pc out [32][80] fp16, overlays OFFW (dead after coordpack)
#define H1_H  22480     // h1     [32][80] fp16, overlays OFFW

typedef _Float16 f16x8 __attribute__((ext_vector_type(8)));
typedef float    f32x4 __attribute__((ext_vector_type(4)));

// one 16x16 output tile per wave: D = W(64x64 f32 global) x act(PH [px][80] f16) + bias
__device__ inline f32x4 tile_gemm64(const __half* PH, int actH,
                                    const float* __restrict__ W,
                                    const float* __restrict__ Bv,
                                    int m_t, int n_t, int lane) {
    const int row = m_t * 16 + (lane & 15);
    const int kg  = (lane >> 4) * 8;
    const float* wr = W + row * 64 + kg;
    float4 wa0 = *reinterpret_cast<const float4*>(wr);
    float4 wa1 = *reinterpret_cast<const float4*>(wr + 4);
    float4 wb0 = *reinterpret_cast<const float4*>(wr + 32);
    float4 wb1 = *reinterpret_cast<const float4*>(wr + 36);
    f16x8 a0, a1;
    a0[0]=(_Float16)wa0.x; a0[1]=(_Float16)wa0.y; a0[2]=(_Float16)wa0.z; a0[3]=(_Float16)wa0.w;
    a0[4]=(_Float16)wa1.x; a0[5]=(_Float16)wa1.y; a0[6]=(_Float16)wa1.z; a0[7]=(_Float16)wa1.w;
    a1[0]=(_Float16)wb0.x; a1[1]=(_Float16)wb0.y; a1[2]=(_Float16)wb0.z; a1[3]=(_Float16)wb0.w;
    a1[4]=(_Float16)wb1.x; a1[5]=(_Float16)wb1.y; a1[6]=(_Float16)wb1.z; a1[7]=(_Float16)wb1.w;
    const int px = n_t * 16 + (lane & 15);
    f16x8 b0 = *reinterpret_cast<const f16x8*>(&PH[actH + px * 80 + kg]);
    f16x8 b1 = *reinterpret_cast<const f16x8*>(&PH[actH + px * 80 + 32 + kg]);
    f32x4 d;
    const int r0 = m_t * 16 + ((lane >> 4) << 2);
    #pragma unroll
    for (int r = 0; r < 4; ++r) d[r] = Bv[r0 + r];
    d = __builtin_amdgcn_mfma_f32_16x16x32_f16(a0, b0, d, 0, 0, 0);
    d = __builtin_amdgcn_mfma_f32_16x16x32_f16(a1, b1, d, 0, 0, 0);
    return d;
}

// ---------------- fused main: 1 block (8 waves, 512 thr) per HALF row; 2 blocks/CU ----------------
__global__ __launch_bounds__(512, 4) void crossd_main(
    const float* __restrict__ x,
    const float* __restrict__ p_n,
    const float* __restrict__ dwf_w, const float* __restrict__ dwf_b,
    const float* __restrict__ pwf_w, const float* __restrict__ pwf_b,
    const float* __restrict__ dwc_w, const float* __restrict__ dwc_b,
    const float* __restrict__ pwc_w, const float* __restrict__ pwc_b,
    const float* __restrict__ dwm_w, const float* __restrict__ dwm_b,
    const float* __restrict__ pwm_w, const float* __restrict__ pwm_b,
    const float* __restrict__ pc_w, const float* __restrict__ pc_b,
    const float* __restrict__ w1, const float* __restrict__ b1,
    const float* __restrict__ w2, const float* __restrict__ b2,
    float* __restrict__ out)
{
    __shared__ float P[POOLW];
    uint32_t* PU = reinterpret_cast<uint32_t*>(P);
    __half*   PH = reinterpret_cast<__half*>(P);
    const int tid  = threadIdx.x;
    const int lane = tid & 63;
    const int wv   = __builtin_amdgcn_readfirstlane(tid >> 6);   // 0..7
    // XCD-aware swizzle: 512 blocks, 8 XCDs (round-robin wg%8). Give each XCD a
    // CONTIGUOUS range of 64 logical block-ids = 32 consecutive y-rows of one
    // batch-half, whose 5-row windows overlap ~80% -> L2-resident (~0.6 MB/XCD).
    // 512 % 8 == 0 -> this remap is bijective.
    const int wg  = blockIdx.x;
    const int bid = ((wg & 7) << 6) | (wg >> 3);                 // logical block id
    const int xh = bid & 1, y = (bid >> 1) & 63, b = bid >> 7;
    const int x0 = xh << 5;                                      // half-row origin
    const int ry0 = min(max(y - 1, 0), 59);                      // window rows ry0..ry0+4
    const float* xb = x + (size_t)b * (64 * HH * WW);            // NCHW batch base

    // ---- phase 0: stage 5-row x 36-col fp16 window DIRECTLY from NCHW x ----
    {
        // idx = (j, c, col), col fastest -> coalesced 144 B row segments per (j,c)
        for (int idx = tid; idx < 5 * 64 * 36; idx += 512) {
            int j   = idx / (64 * 36);
            int rem = idx - j * (64 * 36);
            int c   = rem / 36;
            int col = rem - c * 36;
            int gcol = min(max(x0 - 1 + col, 0), 63);
            float v = xb[((size_t)c * HH + (ry0 + j)) * WW + gcol];
            PH[(j * 36 + col) * 68 + c] = __float2half(v);
        }
        for (int i = tid; i < 25 * 33 + 1; i += 512) P[CMAP + i] = 0.0f;  // CMAP + FLBC
    }
    __syncthreads();   // B0

    // ---- depthwise 3x3 from window: wave = 4 px, lane = ch; fp16 t-buffers [32][80] ----
    {
        const int c = lane;
        float wf9[9], wc9[9], wm9[9];
        #pragma unroll
        for (int k9 = 0; k9 < 9; ++k9) {
            wf9[k9] = dwf_w[c * 9 + k9];
            wc9[k9] = dwc_w[c * 9 + k9];
            wm9[k9] = dwm_w[c * 9 + k9];
        }
        const float bf = dwf_b[c], bc = dwc_b[c], bm = dwm_b[c];
        #pragma unroll
        for (int i = 0; i < 4; ++i) {
            const int pl = wv * 4 + i;          // local px
            const int pg = x0 + pl;             // global px
            float af = bf, ac = bc, am = bm;
            #pragma unroll
            for (int dy = 0; dy < 3; ++dy) {
                int yy = y + dy - 1;
                if (yy < 0 || yy >= HH) continue;
                int j = yy - ry0;
                #pragma unroll
                for (int dx = 0; dx < 3; ++dx) {
                    int xx = pg + dx - 1;
                    if (xx < 0 || xx >= WW) continue;
                    int co = xx - x0 + 1;       // window col 0..33
                    float v = __half2float(PH[(j * 36 + co) * 68 + c]);
                    int k = dy * 3 + dx;
                    af = fmaf(v, wf9[k], af);
                    ac = fmaf(v, wc9[k], ac);
                    am = fmaf(v, wm9[k], am);
                }
            }
            PH[TF_H + pl * 80 + c] = __float2half(af);
            PH[TC_H + pl * 80 + c] = __float2half(ac);
            PH[TM_H + pl * 80 + c] = __float2half(am);
        }
    }
    __syncthreads();   // B1

    // ---- fused f+c+m pointwise via MFMA: 11 m-tiles x 2 n-tiles over 8 waves ----
    {
        const int n_t = wv & 1;
        const int g   = wv >> 1;
        #pragma unroll
        for (int t = 0; t < 3; ++t) {
            const int m_t = g + t * 4;
            if (m_t < 11) {
                const float *Wb, *Bvb; int rows, actH, r0b, br;
                if (m_t < 2)      { Wb=pwf_w; Bvb=pwf_b; rows=32; actH=TF_H; r0b=m_t*16;     br=0; }
                else if (m_t < 7) { Wb=pwc_w; Bvb=pwc_b; rows=72; actH=TC_H; r0b=(m_t-2)*16; br=1; }
                else              { Wb=pwm_w; Bvb=pwm_b; rows=53; actH=TM_H; r0b=(m_t-7)*16; br=2; }
                const int rl  = min(r0b + (lane & 15), rows - 1);
                const int kg  = (lane >> 4) * 8;
                const float* wr = Wb + rl * 64 + kg;
                float4 wa0 = *reinterpret_cast<const float4*>(wr);
                float4 wa1 = *reinterpret_cast<const float4*>(wr + 4);
                float4 wb0 = *reinterpret_cast<const float4*>(wr + 32);
                float4 wb1 = *reinterpret_cast<const float4*>(wr + 36);
                f16x8 a0, a1;
                a0[0]=(_Float16)wa0.x; a0[1]=(_Float16)wa0.y; a0[2]=(_Float16)wa0.z; a0[3]=(_Float16)wa0.w;
                a0[4]=(_Float16)wa1.x; a0[5]=(_Float16)wa1.y; a0[6]=(_Float16)wa1.z; a0[7]=(_Float16)wa1.w;
                a1[0]=(_Float16)wb0.x; a1[1]=(_Float16)wb0.y; a1[2]=(_Float16)wb0.z; a1[3]=(_Float16)wb0.w;
                a1[4]=(_Float16)wb1.x; a1[5]=(_Float16)wb1.y; a1[6]=(_Float16)wb1.z; a1[7]=(_Float16)wb1.w;
                const int px = n_t * 16 + (lane & 15);
                f16x8 b0 = *reinterpret_cast<const f16x8*>(&PH[actH + px * 80 + kg]);
                f16x8 b1 = *reinterpret_cast<const f16x8*>(&PH[actH + px * 80 + 32 + kg]);
                f32x4 d;
                const int rr0 = r0b + ((lane >> 4) << 2);
                #pragma unroll
                for (int r = 0; r < 4; ++r) d[r] = Bvb[min(rr0 + r, rows - 1)];
                d = __builtin_amdgcn_mfma_f32_16x16x32_f16(a0, b0, d, 0, 0, 0);
                d = __builtin_amdgcn_mfma_f32_16x16x32_f16(a1, b1, d, 0, 0, 0);
                #pragma unroll
                for (int r = 0; r < 4; ++r) {
                    const int rb = rr0 + r;
                    if (rb < rows) {
                        const float v = d[r];
                        if (br == 2)      P[SBW + rb * 35 + px] = v;
                        else {
                            int og = (br == 0) ? rb : 32 + rb;
                            P[OFFW + og * 33 + px] = v;
                        }
                    }
                }
            }
        }
    }
    __syncthreads();   // B2

    // ---- fused gated-softmax + coordpack (cell-map accumulate): wave owns 4 px ----
    #pragma unroll 1
    for (int i = 0; i < 4; ++i) {
        const int pl = wv * 4 + i;
        const float sp = P[SBW + 52 * 35 + pl];
        float z = -1e30f;
        if (lane < 52) {
            float s  = P[SBW + lane * 35 + pl];
            float sg = 1.0f / (1.0f + __expf(-(s - sp) * 10.0f));
            z = s + __logf(sg + 1e-10f);
        }
        float mx = z;
        #pragma unroll
        for (int d = 32; d >= 1; d >>= 1) mx = fmaxf(mx, __shfl_xor(mx, d));
        float e = (lane < 52) ? __expf(z - mx) : 0.0f;
        float sm = e;
        #pragma unroll
        for (int d = 32; d >= 1; d >>= 1) sm += __shfl_xor(sm, d);
        if (lane < 52) {
            const float mo = e / sm;
            const int pg = x0 + pl;
            float sx = (float)pg + p_n[lane]      + P[OFFW + lane * 33 + pl];
            float sy = (float)y  + p_n[52 + lane] + P[OFFW + (52 + lane) * 33 + pl];
            float x0f = floorf(sx), y0f = floorf(sy);
            float wx1 = sx - x0f, wy1 = sy - y0f;
            float wx0 = 1.0f - wx1, wy0 = 1.0f - wy1;
            int xi = (int)x0f, yi = (int)y0f;
            bool vx0 = (xi >= 0)  & (xi <= 63);
            bool vx1 = (xi >= -1) & (xi <= 62);
            bool vy0 = (yi >= 0)  & (yi <= 63);
            bool vy1 = (yi >= -1) & (yi <= 62);
            float m00 = (vy0 & vx0) ? mo * wy0 * wx0 : 0.0f;
            float m01 = (vy0 & vx1) ? mo * wy0 * wx1 : 0.0f;
            float m10 = (vy1 & vx0) ? mo * wy1 * wx0 : 0.0f;
            float m11 = (vy1 & vx1) ? mo * wy1 * wx1 : 0.0f;
            const int i0 = xi - pg + 1, j0 = yi - ry0;
            #define PUSH(m, jj, ii, gx, gy) \
                if (m != 0.0f) { \
                    if ((jj) >= 0 && (jj) <= 4 && (ii) >= 0 && (ii) <= 4) { \
                        atomicAdd(&P[CMAP + ((jj) * 5 + (ii)) * 33 + pl], m); \
                    } else { \
                        uint32_t a = (uint32_t)((gy) * 64 + (gx)); \
                        uint32_t sl = atomicAdd(&PU[FLBC], 1u); \
                        if (sl < 512u) { \
                            PU[FLB + sl * 2]     = a | ((uint32_t)pl << 16); \
                            PU[FLB + sl * 2 + 1] = __float_as_uint(m); \
                        } \
                    } \
                }
            PUSH(m00, j0,     i0,     xi,     yi);
            PUSH(m01, j0,     i0 + 1, xi + 1, yi);
            PUSH(m10, j0 + 1, i0,     xi,     yi + 1);
            PUSH(m11, j0 + 1, i0 + 1, xi + 1, yi + 1);
            #undef PUSH
        }
    }
    __syncthreads();   // B3

    // ---- 25-cell gather: W[cell][px] broadcast x window b64; agg -> fp16 [32][80] ----
    {
        const int sub = lane >> 4;
        const int c4  = lane & 15;
        const int spx = wv * 4 + sub;        // local px
        const int spg = x0 + spx;            // global px
        int co[5];
        #pragma unroll
        for (int i = 0; i < 5; ++i) co[i] = min(max(spg - 1 + i, 0), 63) - x0 + 1;
        float4 agg = make_float4(0.f, 0.f, 0.f, 0.f);
        #pragma unroll
        for (int j = 0; j < 5; ++j) {
            #pragma unroll
            for (int i = 0; i < 5; ++i) {
                float w = P[CMAP + (j * 5 + i) * 33 + spx];
                uint2 u = *reinterpret_cast<const uint2*>(&PH[(j * 36 + co[i]) * 68 + c4 * 4]);
                __half2 hlo = *reinterpret_cast<const __half2*>(&u.x);
                __half2 hhi = *reinterpret_cast<const __half2*>(&u.y);
                float2 flo = __half22float2(hlo), fhi = __half22float2(hhi);
                agg.x = fmaf(w, flo.x, agg.x); agg.y = fmaf(w, flo.y, agg.y);
                agg.z = fmaf(w, fhi.x, agg.z); agg.w = fmaf(w, fhi.y, agg.w);
            }
        }
        // rare out-of-neighborhood fallback (normally count == 0); NCHW scalar reads
        const int cnt = min((int)PU[FLBC], 512);
        for (int e = 0; e < cnt; ++e) {
            uint32_t ea = PU[FLB + e * 2];
            float m = __uint_as_float(PU[FLB + e * 2 + 1]);
            if ((int)(ea >> 16) == spx) {
                int gy = (int)((ea & 0xFFFFu) >> 6), gx = (int)(ea & 63u);
                float v0 = xb[((size_t)(c4 * 4 + 0) * HH + gy) * WW + gx];
                float v1 = xb[((size_t)(c4 * 4 + 1) * HH + gy) * WW + gx];
                float v2 = xb[((size_t)(c4 * 4 + 2) * HH + gy) * WW + gx];
                float v3 = xb[((size_t)(c4 * 4 + 3) * HH + gy) * WW + gx];
                agg.x = fmaf(m, v0, agg.x); agg.y = fmaf(m, v1, agg.y);
                agg.z = fmaf(m, v2, agg.z); agg.w = fmaf(m, v3, agg.w);
            }
        }
        __half2 p0 = __floats2half2_rn(agg.x, agg.y);
        __half2 p1 = __floats2half2_rn(agg.z, agg.w);
        uint2 pk2;
        pk2.x = *reinterpret_cast<uint32_t*>(&p0);
        pk2.y = *reinterpret_cast<uint32_t*>(&p1);
        *reinterpret_cast<uint2*>(&PH[AGG_H + spx * 80 + c4 * 4]) = pk2;
    }
    __syncthreads();   // B4

    // ---- pc 1x1 via MFMA: AGG -> PCB ----
    {
        f32x4 d = tile_gemm64(PH, AGG_H, pc_w, pc_b, wv >> 1, wv & 1, lane);
        const int px = (wv & 1) * 16 + (lane & 15);
        const int o0 = (wv >> 1) * 16 + ((lane >> 4) << 2);
        __half2 p0 = __floats2half2_rn(d[0], d[1]);
        __half2 p1 = __floats2half2_rn(d[2], d[3]);
        uint2 pk2;
        pk2.x = *reinterpret_cast<uint32_t*>(&p0);
        pk2.y = *reinterpret_cast<uint32_t*>(&p1);
        *reinterpret_cast<uint2*>(&PH[PCB_H + px * 80 + o0]) = pk2;
    }
    __syncthreads();   // B5

    // ---- mlp1 (relu) via MFMA: PCB -> H1 ----
    {
        f32x4 d = tile_gemm64(PH, PCB_H, w1, b1, wv >> 1, wv & 1, lane);
        #pragma unroll
        for (int r = 0; r < 4; ++r) d[r] = fmaxf(d[r], 0.0f);
        const int px = (wv & 1) * 16 + (lane & 15);
        const int o0 = (wv >> 1) * 16 + ((lane >> 4) << 2);
        __half2 p0 = __floats2half2_rn(d[0], d[1]);
        __half2 p1 = __floats2half2_rn(d[2], d[3]);
        uint2 pk2;
        pk2.x = *reinterpret_cast<uint32_t*>(&p0);
        pk2.y = *reinterpret_cast<uint32_t*>(&p1);
        *reinterpret_cast<uint2*>(&PH[H1_H + px * 80 + o0]) = pk2;
    }
    __syncthreads();   // B6

    // ---- mlp2 via MFMA + residual + NCHW store ----
    {
        f32x4 d = tile_gemm64(PH, H1_H, w2, b2, wv >> 1, wv & 1, lane);
        const int px = (wv & 1) * 16 + (lane & 15);
        const int o0 = (wv >> 1) * 16 + ((lane >> 4) << 2);
        #pragma unroll
        for (int r = 0; r < 4; ++r) {
            const int o = o0 + r;
            size_t idx = (((size_t)b * 64 + o) * 64 + y) * 64 + x0 + px;
            out[idx] = d[r] + x[idx];
        }
    }
}

extern "C" void kernel_launch(void* const* d_in, const int* in_sizes, int n_in,
                              void* d_out, int out_size, void* d_ws, size_t ws_size,
                              hipStream_t stream) {
    const float* x     = (const float*)d_in[0];
    const float* p_n   = (const float*)d_in[1];
    const float* dwf_w = (const float*)d_in[2];
    const float* dwf_b = (const float*)d_in[3];
    const float* pwf_w = (const float*)d_in[4];
    const float* pwf_b = (const float*)d_in[5];
    const float* dwc_w = (const float*)d_in[6];
    const float* dwc_b = (const float*)d_in[7];
    const float* pwc_w = (const float*)d_in[8];
    const float* pwc_b = (const float*)d_in[9];
    const float* dwm_w = (const float*)d_in[10];
    const float* dwm_b = (const float*)d_in[11];
    const float* pwm_w = (const float*)d_in[12];
    const float* pwm_b = (const float*)d_in[13];
    const float* pc_w  = (const float*)d_in[14];
    const float* pc_b  = (const float*)d_in[15];
    const float* w1    = (const float*)d_in[16];
    const float* b1    = (const float*)d_in[17];
    const float* w2    = (const float*)d_in[18];
    const float* b2    = (const float*)d_in[19];

    float* outp = (float*)d_out;

    hipLaunchKernelGGL(crossd_main, dim3(BB * HH * 2), dim3(512), 0, stream,
                       x, p_n,
                       dwf_w, dwf_b, pwf_w, pwf_b,
                       dwc_w, dwc_b, pwc_w, pwc_b,
                       dwm_w, dwm_b, pwm_w, pwm_b,
                       pc_w, pc_b, w1, b1, w2, b2, outp);
}